// Round 8
// baseline (134.201 us; speedup 1.0000x reference)
//
#include <hip/hip_runtime.h>
#include <math.h>

#define D_FEAT 64
typedef _Float16 v8h __attribute__((ext_vector_type(8)));
typedef _Float16 v4h __attribute__((ext_vector_type(4)));
typedef float v4f __attribute__((ext_vector_type(4)));

static __device__ __forceinline__ v8h u2h8(uint4 u){ v8h v; __builtin_memcpy(&v,&u,16); return v; }
static __device__ __forceinline__ v4h u2h4(uint2 u){ v4h v; __builtin_memcpy(&v,&u,8); return v; }
static __device__ __forceinline__ float f16lo(unsigned int m){
    unsigned short us = (unsigned short)(m & 0xffffu);
    _Float16 h; __builtin_memcpy(&h, &us, 2); return (float)h;
}

// P1: per-node L2 norm; store norm (f32) and NORMALIZED f16 copy of x.
__global__ __launch_bounds__(256)
void agnn_prep1(const float* __restrict__ x, float* __restrict__ nf,
                uint2* __restrict__ xh, int n_nodes) {
    int t = blockIdx.x*blockDim.x + threadIdx.x;
    int node = t >> 4; if (node >= n_nodes) return;
    int l4 = t & 15;
    float4 v = ((const float4*)x)[node*16 + l4];
    float ss = v.x*v.x + v.y*v.y + v.z*v.z + v.w*v.w;
    #pragma unroll
    for (int off = 1; off < 16; off <<= 1) ss += __shfl_xor(ss, off, 64);
    float r = ss > 0.f ? rsqrtf(ss) : 0.f;
    if (l4 == 0) nf[node] = ss * r;     // sqrt(ss)
    auto h0 = __builtin_amdgcn_cvt_pkrtz(v.x*r, v.y*r);
    auto h1 = __builtin_amdgcn_cvt_pkrtz(v.z*r, v.w*r);
    uint2 u; __builtin_memcpy(&u.x, &h0, 4); __builtin_memcpy(&u.y, &h1, 4);
    xh[node*16 + l4] = u;
}

// P2: CSR row offsets (boundary scatter) + per-edge metadata:
// md[e] = (local_row << 16) | f16bits(norm of col node).  +64 pad entries.
__global__ __launch_bounds__(256)
void agnn_prep2(const int* __restrict__ edge_row, const int* __restrict__ edge_col,
                const float* __restrict__ nf, int* __restrict__ row_ptr,
                unsigned int* __restrict__ md, int n_nodes, int n_edges) {
    int e = blockIdx.x*blockDim.x + threadIdx.x;
    if (e < 64) md[n_edges + e] = 0xFFFF0000u;   // rl=0xFFFF never matches
    if (e >= n_edges) return;
    int r1 = edge_row[e];
    int r0 = (e == 0) ? -1 : edge_row[e-1];
    for (int r = r0+1; r <= r1; ++r) row_ptr[r] = e;
    if (e == n_edges-1)
        for (int r = r1+1; r <= n_nodes; ++r) row_ptr[r] = n_edges;
    _Float16 h = (_Float16)nf[edge_col[e]];
    unsigned short us; __builtin_memcpy(&us, &h, 2);
    md[e] = ((unsigned int)(r1 & 15) << 16) | us;
}

// K: fused sim+softmax+SPMM.  One wave per 16-node tile, 2 waves/block.
// Per 32-edge chunk (2 halves of 16):
//  S^T = Xc_hat . Q_hat^T  via mfma_16x16x32 (gathered regs ARE the A operand;
//        C layout: col=lo4=node, row=q*4+reg=edge) -> no relayout for masking.
//  w   = (md.rl==lo4 && in-range) ? exp(beta*z - |beta|) : 0;  w' = w*nc.
//  PV  via mfma 16x16x16 (A k-dist = q*4+j == S^T row dist -> NO P transpose),
//        B = Xc^T staged in wave-private LDS (16 ds_write_b32 + 8 ds_read_b128).
#define XCP_PITCH 144
__global__ __launch_bounds__(128, 6)
void agnn_fused(const float* __restrict__ beta_p,
                const int* __restrict__ edge_col,
                const unsigned int* __restrict__ md,
                const int* __restrict__ row_ptr,
                const uint4* __restrict__ xh4,
                float* __restrict__ out, int n_nodes) {
    __shared__ char lds_raw[2 * 32 * XCP_PITCH];
    int wid = threadIdx.x >> 6, lane = threadIdx.x & 63;
    int q = lane >> 4, lo4 = lane & 15;
    char* XCP = lds_raw + wid * 32 * XCP_PITCH;

    int t0 = (blockIdx.x*2 + wid) * 16;
    if (t0 >= n_nodes) return;

    int qn = t0 + lo4; if (qn >= n_nodes) qn = n_nodes - 1;
    v8h b0 = u2h8(xh4[(size_t)qn*8 + q]);
    v8h b1 = u2h8(xh4[(size_t)qn*8 + 4 + q]);
    float beta  = beta_p[0];
    float shift = fabsf(beta);
    int te = t0 + 16; if (te > n_nodes) te = n_nodes;
    int es = row_ptr[t0];
    int L  = row_ptr[te] - es;

    v4f o0={0,0,0,0}, o1={0,0,0,0}, o2={0,0,0,0}, o3={0,0,0,0};
    float s = 0.f;
    unsigned int selp = (lo4 & 1) ? 0x07060302u : 0x05040100u;

    for (int base = 0; base < L; base += 32) {
        int i0 = base + lo4;
        int e0 = es + (i0 < L ? i0 : 0);
        int i1 = base + 16 + lo4;
        int e1 = es + (i1 < L ? i1 : 0);
        int c0 = edge_col[e0];
        int c1 = edge_col[e1];
        uint4 A00 = xh4[(size_t)c0*8 + q];
        uint4 A01 = xh4[(size_t)c0*8 + 4 + q];
        uint4 A10 = xh4[(size_t)c1*8 + q];
        uint4 A11 = xh4[(size_t)c1*8 + 4 + q];
        int mb = es + base + 4*q;
        unsigned int m00 = md[mb+0],  m01 = md[mb+1],  m02 = md[mb+2],  m03 = md[mb+3];
        unsigned int m10 = md[mb+16], m11 = md[mb+17], m12 = md[mb+18], m13 = md[mb+19];

        v4f z0 = {0,0,0,0};
        z0 = __builtin_amdgcn_mfma_f32_16x16x32_f16(u2h8(A00), b0, z0, 0,0,0);
        z0 = __builtin_amdgcn_mfma_f32_16x16x32_f16(u2h8(A01), b1, z0, 0,0,0);
        v4f z1 = {0,0,0,0};
        z1 = __builtin_amdgcn_mfma_f32_16x16x32_f16(u2h8(A10), b0, z1, 0,0,0);
        z1 = __builtin_amdgcn_mfma_f32_16x16x32_f16(u2h8(A11), b1, z1, 0,0,0);

        {   // stage Xc^T: rows = feat-pair, cols = edge
            unsigned int colA = lo4*4, colB = (16+lo4)*4;
            char* pA = XCP + (4*q)*XCP_PITCH;
            char* pB = XCP + (16+4*q)*XCP_PITCH;
            *(unsigned int*)(pA + 0*XCP_PITCH + colA) = A00.x;
            *(unsigned int*)(pA + 1*XCP_PITCH + colA) = A00.y;
            *(unsigned int*)(pA + 2*XCP_PITCH + colA) = A00.z;
            *(unsigned int*)(pA + 3*XCP_PITCH + colA) = A00.w;
            *(unsigned int*)(pB + 0*XCP_PITCH + colA) = A01.x;
            *(unsigned int*)(pB + 1*XCP_PITCH + colA) = A01.y;
            *(unsigned int*)(pB + 2*XCP_PITCH + colA) = A01.z;
            *(unsigned int*)(pB + 3*XCP_PITCH + colA) = A01.w;
            *(unsigned int*)(pA + 0*XCP_PITCH + colB) = A10.x;
            *(unsigned int*)(pA + 1*XCP_PITCH + colB) = A10.y;
            *(unsigned int*)(pA + 2*XCP_PITCH + colB) = A10.z;
            *(unsigned int*)(pA + 3*XCP_PITCH + colB) = A10.w;
            *(unsigned int*)(pB + 0*XCP_PITCH + colB) = A11.x;
            *(unsigned int*)(pB + 1*XCP_PITCH + colB) = A11.y;
            *(unsigned int*)(pB + 2*XCP_PITCH + colB) = A11.z;
            *(unsigned int*)(pB + 3*XCP_PITCH + colB) = A11.w;
        }

        int lim0 = L - base - 4*q;      // reg r of half0 valid iff r < lim0
        int lim1 = lim0 - 16;
        float w00 = (0 < lim0 && (m00>>16)==(unsigned)lo4) ? __expf(fmaf(beta, z0[0], -shift)) : 0.f;
        float w01 = (1 < lim0 && (m01>>16)==(unsigned)lo4) ? __expf(fmaf(beta, z0[1], -shift)) : 0.f;
        float w02 = (2 < lim0 && (m02>>16)==(unsigned)lo4) ? __expf(fmaf(beta, z0[2], -shift)) : 0.f;
        float w03 = (3 < lim0 && (m03>>16)==(unsigned)lo4) ? __expf(fmaf(beta, z0[3], -shift)) : 0.f;
        float w10 = (0 < lim1 && (m10>>16)==(unsigned)lo4) ? __expf(fmaf(beta, z1[0], -shift)) : 0.f;
        float w11 = (1 < lim1 && (m11>>16)==(unsigned)lo4) ? __expf(fmaf(beta, z1[1], -shift)) : 0.f;
        float w12 = (2 < lim1 && (m12>>16)==(unsigned)lo4) ? __expf(fmaf(beta, z1[2], -shift)) : 0.f;
        float w13 = (3 < lim1 && (m13>>16)==(unsigned)lo4) ? __expf(fmaf(beta, z1[3], -shift)) : 0.f;
        s += (w00+w01) + (w02+w03) + (w10+w11) + (w12+w13);

        v4h pa0, pa1;
        {
            auto a = __builtin_amdgcn_cvt_pkrtz(w00*f16lo(m00), w01*f16lo(m01));
            auto b = __builtin_amdgcn_cvt_pkrtz(w02*f16lo(m02), w03*f16lo(m03));
            pa0[0]=a[0]; pa0[1]=a[1]; pa0[2]=b[0]; pa0[3]=b[1];
            auto c = __builtin_amdgcn_cvt_pkrtz(w10*f16lo(m10), w11*f16lo(m11));
            auto d = __builtin_amdgcn_cvt_pkrtz(w12*f16lo(m12), w13*f16lo(m13));
            pa1[0]=c[0]; pa1[1]=c[1]; pa1[2]=d[0]; pa1[3]=d[1];
        }

        // PV: O[node][feat] += P.Xc ; B from LDS (b128 + perm parity select)
        const char* rbase_p = XCP + (lo4>>1)*XCP_PITCH + 16*q;
        {
            const char* rp = rbase_p;
            uint4 d0 = *(const uint4*)rp;
            uint4 d1 = *(const uint4*)(rp + 64);
            uint2 bb0 = { __builtin_amdgcn_perm(d0.y, d0.x, selp), __builtin_amdgcn_perm(d0.w, d0.z, selp) };
            uint2 bb1 = { __builtin_amdgcn_perm(d1.y, d1.x, selp), __builtin_amdgcn_perm(d1.w, d1.z, selp) };
            o0 = __builtin_amdgcn_mfma_f32_16x16x16f16(pa0, u2h4(bb0), o0, 0,0,0);
            o0 = __builtin_amdgcn_mfma_f32_16x16x16f16(pa1, u2h4(bb1), o0, 0,0,0);
        }
        {
            const char* rp = rbase_p + 8*XCP_PITCH;
            uint4 d0 = *(const uint4*)rp;
            uint4 d1 = *(const uint4*)(rp + 64);
            uint2 bb0 = { __builtin_amdgcn_perm(d0.y, d0.x, selp), __builtin_amdgcn_perm(d0.w, d0.z, selp) };
            uint2 bb1 = { __builtin_amdgcn_perm(d1.y, d1.x, selp), __builtin_amdgcn_perm(d1.w, d1.z, selp) };
            o1 = __builtin_amdgcn_mfma_f32_16x16x16f16(pa0, u2h4(bb0), o1, 0,0,0);
            o1 = __builtin_amdgcn_mfma_f32_16x16x16f16(pa1, u2h4(bb1), o1, 0,0,0);
        }
        {
            const char* rp = rbase_p + 16*XCP_PITCH;
            uint4 d0 = *(const uint4*)rp;
            uint4 d1 = *(const uint4*)(rp + 64);
            uint2 bb0 = { __builtin_amdgcn_perm(d0.y, d0.x, selp), __builtin_amdgcn_perm(d0.w, d0.z, selp) };
            uint2 bb1 = { __builtin_amdgcn_perm(d1.y, d1.x, selp), __builtin_amdgcn_perm(d1.w, d1.z, selp) };
            o2 = __builtin_amdgcn_mfma_f32_16x16x16f16(pa0, u2h4(bb0), o2, 0,0,0);
            o2 = __builtin_amdgcn_mfma_f32_16x16x16f16(pa1, u2h4(bb1), o2, 0,0,0);
        }
        {
            const char* rp = rbase_p + 24*XCP_PITCH;
            uint4 d0 = *(const uint4*)rp;
            uint4 d1 = *(const uint4*)(rp + 64);
            uint2 bb0 = { __builtin_amdgcn_perm(d0.y, d0.x, selp), __builtin_amdgcn_perm(d0.w, d0.z, selp) };
            uint2 bb1 = { __builtin_amdgcn_perm(d1.y, d1.x, selp), __builtin_amdgcn_perm(d1.w, d1.z, selp) };
            o3 = __builtin_amdgcn_mfma_f32_16x16x16f16(pa0, u2h4(bb0), o3, 0,0,0);
            o3 = __builtin_amdgcn_mfma_f32_16x16x16f16(pa1, u2h4(bb1), o3, 0,0,0);
        }
    }

    // s currently per (node=lo4) partial across quads -> reduce over quads
    s += __shfl_xor(s, 16, 64);
    s += __shfl_xor(s, 32, 64);

    #pragma unroll
    for (int r = 0; r < 4; ++r) {
        float sr = __shfl(s, 4*q + r, 64);     // sum for node t0+4q+r
        float inv = sr > 0.f ? 1.f/sr : 0.f;
        int node = t0 + 4*q + r;
        if (node < n_nodes) {
            float* p = out + (size_t)node*64 + lo4;
            p[0]  = o0[r]*inv;
            p[16] = o1[r]*inv;
            p[32] = o2[r]*inv;
            p[48] = o3[r]*inv;
        }
    }
}

extern "C" void kernel_launch(void* const* d_in, const int* in_sizes, int n_in,
                              void* d_out, int out_size, void* d_ws, size_t ws_size,
                              hipStream_t stream) {
    const float* x        = (const float*)d_in[0];
    const float* beta     = (const float*)d_in[1];
    const int*   edge_row = (const int*)d_in[2];
    const int*   edge_col = (const int*)d_in[3];
    float* out = (float*)d_out;

    int n_nodes = in_sizes[0] / D_FEAT;
    int n_edges = in_sizes[2];

    // ws: nf f32[N] | row_ptr i32[N+1] | md u32[E+64] | xh f16[N*64]
    char* ws = (char*)d_ws;
    float* nf = (float*)ws;
    size_t off0 = ((size_t)n_nodes*sizeof(float) + 255) & ~(size_t)255;
    int* row_ptr = (int*)(ws + off0);
    size_t off1 = off0 + (((size_t)(n_nodes+1)*sizeof(int) + 255) & ~(size_t)255);
    unsigned int* md = (unsigned int*)(ws + off1);
    size_t off2 = off1 + (((size_t)(n_edges+64)*sizeof(unsigned int) + 255) & ~(size_t)255);
    uint2* xh = (uint2*)(ws + off2);

    {   // P1: norms + normalized f16 copy
        long long threads = (long long)n_nodes * 16;
        int blocks = (int)((threads + 255) / 256);
        agnn_prep1<<<blocks, 256, 0, stream>>>(x, nf, xh, n_nodes);
    }
    {   // P2: row_ptr + md
        int blocks = (n_edges + 255) / 256;
        agnn_prep2<<<blocks, 256, 0, stream>>>(edge_row, edge_col, nf, row_ptr,
                                               md, n_nodes, n_edges);
    }
    {   // fused: one wave per 16-node tile, 2 waves per block
        int tiles  = (n_nodes + 15) / 16;
        int blocks = (tiles + 1) / 2;
        agnn_fused<<<blocks, 128, 0, stream>>>(beta, edge_col, md, row_ptr,
                                               (const uint4*)xh, out, n_nodes);
    }
}